// Round 4
// baseline (372.621 us; speedup 1.0000x reference)
//
#include <hip/hip_runtime.h>
#include <stdint.h>

typedef __attribute__((ext_vector_type(8))) short short8v;   // 8 x bf16 (4 VGPR)
typedef __attribute__((ext_vector_type(4))) float f32x4;

__device__ __forceinline__ unsigned short f2bf(float f) {
  union { float f; unsigned int i; } v; v.f = f;
  unsigned int x = v.i;
  x += 0x7FFFu + ((x >> 16) & 1u);   // round-to-nearest-even
  return (unsigned short)(x >> 16);
}

// ws float offsets
#define WSF_VS 0         // [256][256] fp32 (row 255 zeroed)
#define WSF_SS 65536     // [4][64][64] fp32 Gram: SS[g*4096 + j*64 + i] = v_i.v_j (i<j)
#define WSF_A  81920     // [256][256] fp32: row g*64+j = a_j of group g
// d_out float offsets (scratch; overwritten by y later)
#define OF_P0T 0
#define OF_P1  65536
#define OF_P2T 131072
#define OF_P3  196608
#define OF_P01T 262144
#define OF_P23  327680

// ---------------------------------------------------------------------------
// K1: blocks 0..254: Vs[k] = sqrt(2/(||vfull||^2+1e-16)) * vfull  (vfull = left-
// padded with ones). Block 255: Vs row 255 = 0 (null reflector pad).
// Block 256: tail passthrough (log_det_jac, z).
// ---------------------------------------------------------------------------
__global__ void __launch_bounds__(256) prep_kernel(const float* __restrict__ V,
                                                   float* __restrict__ Vs,
                                                   const float* __restrict__ ldj,
                                                   const float* __restrict__ z,
                                                   float* __restrict__ out) {
  const int k = blockIdx.x;
  const int c = threadIdx.x;
  if (k == 256) {
    if (c < 32) out[33554432u + c] = ldj[c];
    out[33554464u + c] = z[c];
    out[33554464u + 256u + c] = z[256u + c];
    return;
  }
  if (k == 255) { Vs[255 * 256 + c] = 0.0f; return; }
  float val = (c >= 254 - k) ? V[k * 256 + c] : 1.0f;
  float ss = val * val;
  #pragma unroll
  for (int off = 32; off >= 1; off >>= 1) ss += __shfl_xor(ss, off);
  __shared__ float part[4];
  if ((threadIdx.x & 63) == 0) part[threadIdx.x >> 6] = ss;
  __syncthreads();
  const float tot = part[0] + part[1] + part[2] + part[3];
  const float s = sqrtf(2.0f / (tot + 1e-16f));
  Vs[k * 256 + c] = s * val;
}

// ---------------------------------------------------------------------------
// K2: in-group Gram blocks. Block (istrip, g); wave-uniform row i (s_load),
// per-lane row j (L2-resident). SS[g][j][i] = v_i . v_j for i < j.
// ---------------------------------------------------------------------------
__global__ void __launch_bounds__(256) gram_kernel(const float* __restrict__ Vs,
                                                   float* __restrict__ SS) {
  const int g = blockIdx.y, is = blockIdx.x;
  const int w = threadIdx.x >> 6, j = threadIdx.x & 63;
  #pragma unroll
  for (int ii = 0; ii < 2; ++ii) {
    const int i = is * 8 + w * 2 + ii;
    if (i < j) {
      const f32x4* vi = (const f32x4*)(Vs + (size_t)(g * 64 + i) * 256);
      const f32x4* vj = (const f32x4*)(Vs + (size_t)(g * 64 + j) * 256);
      f32x4 acc = {0.f, 0.f, 0.f, 0.f};
      #pragma unroll
      for (int q = 0; q < 64; ++q) {
        const f32x4 a = vi[q], b = vj[q];
        acc[0] += a[0] * b[0]; acc[1] += a[1] * b[1];
        acc[2] += a[2] * b[2]; acc[3] += a[3] * b[3];
      }
      SS[(g * 64 + j) * 64 + i] = (acc[0] + acc[1]) + (acc[2] + acc[3]);
    }
  }
}

// ---------------------------------------------------------------------------
// K3: group solve (compact-WY): a_j = v_j - sum_{i<j} S[i][j] a_i.
// Thread = dim d; a[] fully unrolled static registers; weights are
// wave-uniform scalar loads. No cross-lane ops at all.
// ---------------------------------------------------------------------------
__global__ void __launch_bounds__(256) solve_kernel(const float* __restrict__ Vs,
                                                    const float* __restrict__ SS,
                                                    float* __restrict__ A) {
  const int g = blockIdx.x, d = threadIdx.x;
  const float* Vg = Vs + (size_t)g * 64 * 256;
  const float* Sg = SS + g * 64 * 64;
  float a[64];
  a[0] = Vg[d];
  #pragma unroll
  for (int j = 1; j < 64; ++j) {
    float s0 = 0.f, s1 = 0.f, s2 = 0.f, s3 = 0.f;
    #pragma unroll
    for (int i = 0; i < 64; i += 4) {
      if (i + 0 < j) s0 += Sg[j * 64 + i + 0] * a[i + 0];
      if (i + 1 < j) s1 += Sg[j * 64 + i + 1] * a[i + 1];
      if (i + 2 < j) s2 += Sg[j * 64 + i + 2] * a[i + 2];
      if (i + 3 < j) s3 += Sg[j * 64 + i + 3] * a[i + 3];
    }
    a[j] = Vg[j * 256 + d] - ((s0 + s1) + (s2 + s3));
  }
  #pragma unroll
  for (int j = 0; j < 64; ++j) A[(size_t)(g * 64 + j) * 256 + d] = a[j];
}

// ---------------------------------------------------------------------------
// K4: dense group products. Normal (g odd):  P_g[r][c]   = d_rc - sum_j A[j][r] Vs[j][c]
//     Transposed (g even): P_g^T[r][c] = d_rc - sum_j Vs[j][r] A[j][c]
// (same code, operand swap). uniform operand -> s_load; coalesced operand by c.
// ---------------------------------------------------------------------------
__global__ void __launch_bounds__(256) formp_kernel(const float* __restrict__ Vs,
                                                    const float* __restrict__ A,
                                                    float* __restrict__ outF) {
  const int rt = blockIdx.x, g = blockIdx.y;
  const int c = threadIdx.x;
  const bool tr = ((g & 1) == 0);
  const float* uni = (tr ? Vs : A) + (size_t)g * 64 * 256;
  const float* coa = (tr ? A : Vs) + (size_t)g * 64 * 256;
  float* Pg = outF + (size_t)g * 65536;
  float acc[64];
  #pragma unroll
  for (int r = 0; r < 64; ++r) acc[r] = (rt * 64 + r == c) ? 1.0f : 0.0f;
  for (int j = 0; j < 64; ++j) {
    const float v = coa[j * 256 + c];
    const float* ur = uni + j * 256 + rt * 64;
    #pragma unroll
    for (int r = 0; r < 64; ++r) acc[r] -= ur[r] * v;
  }
  #pragma unroll
  for (int r = 0; r < 64; ++r) Pg[(size_t)(rt * 64 + r) * 256 + c] = acc[r];
}

// ---------------------------------------------------------------------------
// K5: pair products. Z[r][c] = sum_k XT[k][r] Y[k][c].
// z=0: P01T = P1^T P0^T  (XT=P1, Y=P0T).  z=1: P23 = P2 P3  (XT=P2T, Y=P3).
// ---------------------------------------------------------------------------
__global__ void __launch_bounds__(256) mulpair_kernel(float* __restrict__ outF) {
  const int ct = blockIdx.x, rt = blockIdx.y, z = blockIdx.z;
  const float* XT = outF + (z == 0 ? OF_P1 : OF_P2T);
  const float* Y  = outF + (z == 0 ? OF_P0T : OF_P3);
  float* Z        = outF + (z == 0 ? OF_P01T : OF_P23);
  const int c  = ct * 64 + (threadIdx.x & 63);
  const int r0 = rt * 64 + (threadIdx.x >> 6) * 16;
  float acc[16];
  #pragma unroll
  for (int q = 0; q < 16; ++q) acc[q] = 0.f;
  for (int k = 0; k < 256; ++k) {
    const float yv = Y[k * 256 + c];
    const float* xr = XT + k * 256 + r0;
    #pragma unroll
    for (int q = 0; q < 16; ++q) acc[q] += xr[q] * yv;
  }
  #pragma unroll
  for (int q = 0; q < 16; ++q) Z[(size_t)(r0 + q) * 256 + c] = acc[q];
}

// ---------------------------------------------------------------------------
// K6: W = P01 * P23 (XT=P01T, Y=P23) -> Wb bf16.
// ---------------------------------------------------------------------------
__global__ void __launch_bounds__(256) mulfinal_kernel(const float* __restrict__ outF,
                                                       unsigned short* __restrict__ Wb) {
  const int ct = blockIdx.x, rt = blockIdx.y;
  const float* XT = outF + OF_P01T;
  const float* Y  = outF + OF_P23;
  const int c  = ct * 64 + (threadIdx.x & 63);
  const int r0 = rt * 64 + (threadIdx.x >> 6) * 16;
  float acc[16];
  #pragma unroll
  for (int q = 0; q < 16; ++q) acc[q] = 0.f;
  for (int k = 0; k < 256; ++k) {
    const float yv = Y[k * 256 + c];
    const float* xr = XT + k * 256 + r0;
    #pragma unroll
    for (int q = 0; q < 16; ++q) acc[q] += xr[q] * yv;
  }
  #pragma unroll
  for (int q = 0; q < 16; ++q) Wb[(size_t)(r0 + q) * 256 + c] = f2bf(acc[q]);
}

// ---------------------------------------------------------------------------
// K7: conv (unchanged from round 3): y[b][o][n] = sum_c W[o][c] x[b][c][n].
// ---------------------------------------------------------------------------
__global__ void __launch_bounds__(512) conv_kernel(const float* __restrict__ x,
                                                   const unsigned short* __restrict__ Wb,
                                                   float* __restrict__ y) {
  __shared__ unsigned int lds[2048];   // 64 rows x 32 dwords = 8 KB

  const int b  = blockIdx.y;
  const int n0 = blockIdx.x * 64;
  const int t  = threadIdx.x;
  const int w  = t >> 6;
  const int l  = t & 63;
  const int lr = l & 15;
  const int lg = l >> 4;
  const int nq = t & 15;        // staging n-quad
  const int kb = t >> 4;        // staging k-pair row index 0..31

  const float* __restrict__ xb = x + (size_t)b * (256u * 4096u);
  float* __restrict__ yb = y + (size_t)b * (256u * 4096u);

  f32x4 acc[2][4];
  #pragma unroll
  for (int i = 0; i < 2; ++i)
    #pragma unroll
    for (int j = 0; j < 4; ++j)
      acc[i][j] = (f32x4){0.f, 0.f, 0.f, 0.f};

  f32x4 r0, r1;
  {
    const f32x4* p = (const f32x4*)(xb + (size_t)(2 * kb) * 4096 + n0) + nq;
    r0 = p[0];
    r1 = p[1024];
  }

  for (int T = 0; T < 4; ++T) {
    unsigned int packed[4];
    #pragma unroll
    for (int j = 0; j < 4; ++j)
      packed[j] = (unsigned int)f2bf(r0[j]) | ((unsigned int)f2bf(r1[j]) << 16);

    if (T) __syncthreads();
    #pragma unroll
    for (int jj = 0; jj < 4; ++jj) {
      const int j = (jj + nq) & 3;
      const int n = 4 * nq + j;
      const int dw = n * 32 + ((((kb >> 2) ^ (n & 7)) << 2) | (kb & 3));
      lds[dw] = packed[j];
    }
    __syncthreads();

    if (T < 3) {
      const f32x4* p = (const f32x4*)(xb + (size_t)(64 * (T + 1) + 2 * kb) * 4096 + n0) + nq;
      r0 = p[0];
      r1 = p[1024];
    }

    #pragma unroll
    for (int s = 0; s < 2; ++s) {
      short8v a[2], bb[4];
      #pragma unroll
      for (int i = 0; i < 2; ++i)
        a[i] = *(const short8v*)(Wb + (size_t)(32 * w + 16 * i + lr) * 256
                                 + 64 * T + 32 * s + 8 * lg);
      #pragma unroll
      for (int jn = 0; jn < 4; ++jn) {
        const int n = 16 * jn + lr;
        const int dw = n * 32 + ((((s << 2) + lg) ^ (lr & 7)) << 2);
        bb[jn] = *(const short8v*)(&lds[dw]);
      }
      #pragma unroll
      for (int i = 0; i < 2; ++i)
        #pragma unroll
        for (int jn = 0; jn < 4; ++jn)
          acc[i][jn] = __builtin_amdgcn_mfma_f32_16x16x32_bf16(a[i], bb[jn], acc[i][jn], 0, 0, 0);
    }
  }

  #pragma unroll
  for (int i = 0; i < 2; ++i)
    #pragma unroll
    for (int jn = 0; jn < 4; ++jn)
      #pragma unroll
      for (int rr = 0; rr < 4; ++rr) {
        const int o = 32 * w + 16 * i + 4 * lg + rr;
        yb[(size_t)o * 4096 + n0 + 16 * jn + lr] = acc[i][jn][rr];
      }
}

extern "C" void kernel_launch(void* const* d_in, const int* in_sizes, int n_in,
                              void* d_out, int out_size, void* d_ws, size_t ws_size,
                              hipStream_t stream) {
  const float* x   = (const float*)d_in[0];  // fp32 [32,256,64,64]
  const float* ldj = (const float*)d_in[1];  // fp32 [32]
  const float* z   = (const float*)d_in[2];  // fp32 [32,16]
  const float* V   = (const float*)d_in[3];  // fp32 [255,256]
  float* out = (float*)d_out;

  float* wsF = (float*)d_ws;
  float* Vs = wsF + WSF_VS;
  float* SS = wsF + WSF_SS;
  float* A  = wsF + WSF_A;
  unsigned short* Wb = (unsigned short*)((char*)d_ws + (size_t)(WSF_A + 65536) * 4);

  prep_kernel<<<257, 256, 0, stream>>>(V, Vs, ldj, z, out);
  gram_kernel<<<dim3(8, 4), 256, 0, stream>>>(Vs, SS);
  solve_kernel<<<4, 256, 0, stream>>>(Vs, SS, A);
  formp_kernel<<<dim3(4, 4), 256, 0, stream>>>(Vs, A, out);
  mulpair_kernel<<<dim3(4, 4, 2), 256, 0, stream>>>(out);
  mulfinal_kernel<<<dim3(4, 4), 256, 0, stream>>>(out, Wb);
  dim3 grid(64, 32);
  conv_kernel<<<grid, 512, 0, stream>>>(x, Wb, out);
}

// Round 5
// 250.252 us; speedup vs baseline: 1.4890x; 1.4890x over previous
//
#include <hip/hip_runtime.h>
#include <stdint.h>

typedef __attribute__((ext_vector_type(8))) short short8v;   // 8 x bf16 (4 VGPR)
typedef __attribute__((ext_vector_type(4))) float f32x4;

__device__ __forceinline__ unsigned short f2bf(float f) {
  union { float f; unsigned int i; } v; v.f = f;
  unsigned int x = v.i;
  x += 0x7FFFu + ((x >> 16) & 1u);   // round-to-nearest-even
  return (unsigned short)(x >> 16);
}

// ws float offsets
#define WSF_VS 0         // [256][256] fp32 (row 255 zeroed)
#define WSF_SS 65536     // [4][64][64] fp32 Gram: SS[g*4096 + j*64 + i] = v_i.v_j (i<j)
#define WSF_A  81920     // [256][256] fp32: row g*64+j = a_j of group g
// d_out float offsets (scratch; overwritten by y later)
#define OF_P0T 0
#define OF_P1  65536
#define OF_P2T 131072
#define OF_P3  196608
#define OF_P01T 262144
#define OF_P23  327680

// ---------------------------------------------------------------------------
// K1: blocks 0..254: Vs[k] = sqrt(2/(||vfull||^2+1e-16)) * vfull  (vfull = left-
// padded with ones). Block 255: Vs row 255 = 0. Block 256: tail passthrough.
// ---------------------------------------------------------------------------
__global__ void __launch_bounds__(256) prep_kernel(const float* __restrict__ V,
                                                   float* __restrict__ Vs,
                                                   const float* __restrict__ ldj,
                                                   const float* __restrict__ z,
                                                   float* __restrict__ out) {
  const int k = blockIdx.x;
  const int c = threadIdx.x;
  if (k == 256) {
    if (c < 32) out[33554432u + c] = ldj[c];
    out[33554464u + c] = z[c];
    out[33554464u + 256u + c] = z[256u + c];
    return;
  }
  if (k == 255) { Vs[255 * 256 + c] = 0.0f; return; }
  float val = (c >= 254 - k) ? V[k * 256 + c] : 1.0f;
  float ss = val * val;
  #pragma unroll
  for (int off = 32; off >= 1; off >>= 1) ss += __shfl_xor(ss, off);
  __shared__ float part[4];
  if ((threadIdx.x & 63) == 0) part[threadIdx.x >> 6] = ss;
  __syncthreads();
  const float tot = part[0] + part[1] + part[2] + part[3];
  const float s = sqrtf(2.0f / (tot + 1e-16f));
  Vs[k * 256 + c] = s * val;
}

// ---------------------------------------------------------------------------
// K2: in-group Gram blocks. SS[g][j][i] = v_i . v_j for i < j.
// ---------------------------------------------------------------------------
__global__ void __launch_bounds__(256) gram_kernel(const float* __restrict__ Vs,
                                                   float* __restrict__ SS) {
  const int g = blockIdx.y, is = blockIdx.x;
  const int w = threadIdx.x >> 6, j = threadIdx.x & 63;
  #pragma unroll
  for (int ii = 0; ii < 2; ++ii) {
    const int i = is * 8 + w * 2 + ii;
    if (i < j) {
      const f32x4* vi = (const f32x4*)(Vs + (size_t)(g * 64 + i) * 256);
      const f32x4* vj = (const f32x4*)(Vs + (size_t)(g * 64 + j) * 256);
      f32x4 acc = {0.f, 0.f, 0.f, 0.f};
      #pragma unroll
      for (int q = 0; q < 64; ++q) {
        const f32x4 a = vi[q], b = vj[q];
        acc[0] += a[0] * b[0]; acc[1] += a[1] * b[1];
        acc[2] += a[2] * b[2]; acc[3] += a[3] * b[3];
      }
      SS[(g * 64 + j) * 64 + i] = (acc[0] + acc[1]) + (acc[2] + acc[3]);
    }
  }
}

// ---------------------------------------------------------------------------
// K3: group solve (compact-WY): a_j = v_j - sum_{i<j} S[j][i] a_i.
// Thread = dim d. History a_0[d]..a_63[d] lives in LDS (thread-private
// column -> no barriers, conflict-free: d-contiguous dwords, 2 lanes/bank).
// Weights Sg[j*64+i] are wave-uniform s_loads. No register arrays.
// ---------------------------------------------------------------------------
__global__ void __launch_bounds__(256) solve_kernel(const float* __restrict__ Vs,
                                                    const float* __restrict__ SS,
                                                    float* __restrict__ A) {
  __shared__ float As[64][256];    // 64 KB
  const int g = blockIdx.x, d = threadIdx.x;
  const float* __restrict__ Vg = Vs + (size_t)g * 64 * 256;
  const float* __restrict__ Sg = SS + g * 4096;
  {
    const float a0 = Vg[d];
    As[0][d] = a0;
    A[(size_t)(g * 64) * 256 + d] = a0;
  }
  for (int j = 1; j < 64; ++j) {
    float s0 = 0.f, s1 = 0.f;
    #pragma unroll 4
    for (int i = 0; i < j - 1; i += 2) {      // paired to break the FMA chain
      s0 += Sg[j * 64 + i]     * As[i][d];
      s1 += Sg[j * 64 + i + 1] * As[i + 1][d];
    }
    if (j & 1) s0 += Sg[j * 64 + (j - 1)] * As[j - 1][d];
    const float aj = Vg[j * 256 + d] - (s0 + s1);
    As[j][d] = aj;
    A[(size_t)(g * 64 + j) * 256 + d] = aj;
  }
}

// ---------------------------------------------------------------------------
// K4: dense group products, 16 rows/thread (acc[16] stays in registers).
// Normal (g odd):  P_g[r][c]   = d_rc - sum_j A[j][r] Vs[j][c]
// Transposed (g even): P_g^T[r][c] = d_rc - sum_j Vs[j][r] A[j][c]
// ---------------------------------------------------------------------------
__global__ void __launch_bounds__(256) formp_kernel(const float* __restrict__ Vs,
                                                    const float* __restrict__ A,
                                                    float* __restrict__ outF) {
  const int rt = blockIdx.x, g = blockIdx.y;   // rt: 0..15 (16 rows each)
  const int c = threadIdx.x;
  const bool tr = ((g & 1) == 0);
  const float* __restrict__ uni = (tr ? Vs : A) + (size_t)g * 64 * 256;
  const float* __restrict__ coa = (tr ? A : Vs) + (size_t)g * 64 * 256;
  float* __restrict__ Pg = outF + (size_t)g * 65536;
  float acc[16];
  #pragma unroll
  for (int r = 0; r < 16; ++r) acc[r] = (rt * 16 + r == c) ? 1.0f : 0.0f;
  for (int j = 0; j < 64; ++j) {
    const float v = coa[j * 256 + c];
    const float* __restrict__ ur = uni + j * 256 + rt * 16;
    #pragma unroll
    for (int r = 0; r < 16; ++r) acc[r] -= ur[r] * v;
  }
  #pragma unroll
  for (int r = 0; r < 16; ++r) Pg[(size_t)(rt * 16 + r) * 256 + c] = acc[r];
}

// ---------------------------------------------------------------------------
// K5: pair products. Z[r][c] = sum_k XT[k][r] Y[k][c].
// z=0: P01T = P1^T P0^T  (XT=P1, Y=P0T).  z=1: P23 = P2 P3  (XT=P2T, Y=P3).
// ---------------------------------------------------------------------------
__global__ void __launch_bounds__(256) mulpair_kernel(float* __restrict__ outF) {
  const int ct = blockIdx.x, rt = blockIdx.y, z = blockIdx.z;
  const float* __restrict__ XT = outF + (z == 0 ? OF_P1 : OF_P2T);
  const float* __restrict__ Y  = outF + (z == 0 ? OF_P0T : OF_P3);
  float* __restrict__ Z        = outF + (z == 0 ? OF_P01T : OF_P23);
  const int c  = ct * 64 + (threadIdx.x & 63);
  const int r0 = rt * 64 + (threadIdx.x >> 6) * 16;
  float acc[16];
  #pragma unroll
  for (int q = 0; q < 16; ++q) acc[q] = 0.f;
  for (int k = 0; k < 256; ++k) {
    const float yv = Y[k * 256 + c];
    const float* __restrict__ xr = XT + k * 256 + r0;
    #pragma unroll
    for (int q = 0; q < 16; ++q) acc[q] += xr[q] * yv;
  }
  #pragma unroll
  for (int q = 0; q < 16; ++q) Z[(size_t)(r0 + q) * 256 + c] = acc[q];
}

// ---------------------------------------------------------------------------
// K6: W = P01 * P23 (XT=P01T, Y=P23) -> Wb bf16.
// ---------------------------------------------------------------------------
__global__ void __launch_bounds__(256) mulfinal_kernel(const float* __restrict__ outF,
                                                       unsigned short* __restrict__ Wb) {
  const int ct = blockIdx.x, rt = blockIdx.y;
  const float* __restrict__ XT = outF + OF_P01T;
  const float* __restrict__ Y  = outF + OF_P23;
  const int c  = ct * 64 + (threadIdx.x & 63);
  const int r0 = rt * 64 + (threadIdx.x >> 6) * 16;
  float acc[16];
  #pragma unroll
  for (int q = 0; q < 16; ++q) acc[q] = 0.f;
  for (int k = 0; k < 256; ++k) {
    const float yv = Y[k * 256 + c];
    const float* __restrict__ xr = XT + k * 256 + r0;
    #pragma unroll
    for (int q = 0; q < 16; ++q) acc[q] += xr[q] * yv;
  }
  #pragma unroll
  for (int q = 0; q < 16; ++q) Wb[(size_t)(r0 + q) * 256 + c] = f2bf(acc[q]);
}

// ---------------------------------------------------------------------------
// K7: conv: y[b][o][n] = sum_c W[o][c] x[b][c][n]  (unchanged from round 3)
// ---------------------------------------------------------------------------
__global__ void __launch_bounds__(512) conv_kernel(const float* __restrict__ x,
                                                   const unsigned short* __restrict__ Wb,
                                                   float* __restrict__ y) {
  __shared__ unsigned int lds[2048];   // 64 rows x 32 dwords = 8 KB

  const int b  = blockIdx.y;
  const int n0 = blockIdx.x * 64;
  const int t  = threadIdx.x;
  const int w  = t >> 6;
  const int l  = t & 63;
  const int lr = l & 15;
  const int lg = l >> 4;
  const int nq = t & 15;        // staging n-quad
  const int kb = t >> 4;        // staging k-pair row index 0..31

  const float* __restrict__ xb = x + (size_t)b * (256u * 4096u);
  float* __restrict__ yb = y + (size_t)b * (256u * 4096u);

  f32x4 acc[2][4];
  #pragma unroll
  for (int i = 0; i < 2; ++i)
    #pragma unroll
    for (int j = 0; j < 4; ++j)
      acc[i][j] = (f32x4){0.f, 0.f, 0.f, 0.f};

  f32x4 r0, r1;
  {
    const f32x4* p = (const f32x4*)(xb + (size_t)(2 * kb) * 4096 + n0) + nq;
    r0 = p[0];
    r1 = p[1024];
  }

  for (int T = 0; T < 4; ++T) {
    unsigned int packed[4];
    #pragma unroll
    for (int j = 0; j < 4; ++j)
      packed[j] = (unsigned int)f2bf(r0[j]) | ((unsigned int)f2bf(r1[j]) << 16);

    if (T) __syncthreads();
    #pragma unroll
    for (int jj = 0; jj < 4; ++jj) {
      const int j = (jj + nq) & 3;
      const int n = 4 * nq + j;
      const int dw = n * 32 + ((((kb >> 2) ^ (n & 7)) << 2) | (kb & 3));
      lds[dw] = packed[j];
    }
    __syncthreads();

    if (T < 3) {
      const f32x4* p = (const f32x4*)(xb + (size_t)(64 * (T + 1) + 2 * kb) * 4096 + n0) + nq;
      r0 = p[0];
      r1 = p[1024];
    }

    #pragma unroll
    for (int s = 0; s < 2; ++s) {
      short8v a[2], bb[4];
      #pragma unroll
      for (int i = 0; i < 2; ++i)
        a[i] = *(const short8v*)(Wb + (size_t)(32 * w + 16 * i + lr) * 256
                                 + 64 * T + 32 * s + 8 * lg);
      #pragma unroll
      for (int jn = 0; jn < 4; ++jn) {
        const int n = 16 * jn + lr;
        const int dw = n * 32 + ((((s << 2) + lg) ^ (lr & 7)) << 2);
        bb[jn] = *(const short8v*)(&lds[dw]);
      }
      #pragma unroll
      for (int i = 0; i < 2; ++i)
        #pragma unroll
        for (int jn = 0; jn < 4; ++jn)
          acc[i][jn] = __builtin_amdgcn_mfma_f32_16x16x32_bf16(a[i], bb[jn], acc[i][jn], 0, 0, 0);
    }
  }

  #pragma unroll
  for (int i = 0; i < 2; ++i)
    #pragma unroll
    for (int jn = 0; jn < 4; ++jn)
      #pragma unroll
      for (int rr = 0; rr < 4; ++rr) {
        const int o = 32 * w + 16 * i + 4 * lg + rr;
        yb[(size_t)o * 4096 + n0 + 16 * jn + lr] = acc[i][jn][rr];
      }
}

extern "C" void kernel_launch(void* const* d_in, const int* in_sizes, int n_in,
                              void* d_out, int out_size, void* d_ws, size_t ws_size,
                              hipStream_t stream) {
  const float* x   = (const float*)d_in[0];  // fp32 [32,256,64,64]
  const float* ldj = (const float*)d_in[1];  // fp32 [32]
  const float* z   = (const float*)d_in[2];  // fp32 [32,16]
  const float* V   = (const float*)d_in[3];  // fp32 [255,256]
  float* out = (float*)d_out;

  float* wsF = (float*)d_ws;
  float* Vs = wsF + WSF_VS;
  float* SS = wsF + WSF_SS;
  float* A  = wsF + WSF_A;
  unsigned short* Wb = (unsigned short*)((char*)d_ws + (size_t)(WSF_A + 65536) * 4);

  prep_kernel<<<257, 256, 0, stream>>>(V, Vs, ldj, z, out);
  gram_kernel<<<dim3(8, 4), 256, 0, stream>>>(Vs, SS);
  solve_kernel<<<4, 256, 0, stream>>>(Vs, SS, A);
  formp_kernel<<<dim3(16, 4), 256, 0, stream>>>(Vs, A, out);
  mulpair_kernel<<<dim3(4, 4, 2), 256, 0, stream>>>(out);
  mulfinal_kernel<<<dim3(4, 4), 256, 0, stream>>>(out, Wb);
  dim3 grid(64, 32);
  conv_kernel<<<grid, 512, 0, stream>>>(x, Wb, out);
}

// Round 8
// 242.533 us; speedup vs baseline: 1.5364x; 1.0318x over previous
//
#include <hip/hip_runtime.h>
#include <stdint.h>

typedef __attribute__((ext_vector_type(8))) short short8v;   // 8 x bf16 (4 VGPR)
typedef __attribute__((ext_vector_type(4))) float f32x4;

__device__ __forceinline__ unsigned short f2bf(float f) {
  union { float f; unsigned int i; } v; v.f = f;
  unsigned int x = v.i;
  x += 0x7FFFu + ((x >> 16) & 1u);   // round-to-nearest-even
  return (unsigned short)(x >> 16);
}

// ws float offsets
#define WSF_VS 0         // [256][256] fp32 (row 255 zeroed)
#define WSF_SS 65536     // [4][64][64] fp32 Gram: SS[g*4096 + j*64 + i] = v_i.v_j (i<j)
#define WSF_A  81920     // [256][256] fp32: row g*64+j = a_j of group g
// d_out float offsets (scratch; overwritten by y later)
#define OF_P0T 0
#define OF_P1  65536
#define OF_P2T 131072
#define OF_P3  196608
#define OF_P01T 262144
#define OF_P23  327680

// ---------------------------------------------------------------------------
// K1: blocks 0..254: Vs[k] = sqrt(2/(||vfull||^2+1e-16)) * vfull.
// Block 255: Vs row 255 = 0. Block 256: tail passthrough.
// ---------------------------------------------------------------------------
__global__ void __launch_bounds__(256) prep_kernel(const float* __restrict__ V,
                                                   float* __restrict__ Vs,
                                                   const float* __restrict__ ldj,
                                                   const float* __restrict__ z,
                                                   float* __restrict__ out) {
  const int k = blockIdx.x;
  const int c = threadIdx.x;
  if (k == 256) {
    if (c < 32) out[33554432u + c] = ldj[c];
    out[33554464u + c] = z[c];
    out[33554464u + 256u + c] = z[256u + c];
    return;
  }
  if (k == 255) { Vs[255 * 256 + c] = 0.0f; return; }
  float val = (c >= 254 - k) ? V[k * 256 + c] : 1.0f;
  float ss = val * val;
  #pragma unroll
  for (int off = 32; off >= 1; off >>= 1) ss += __shfl_xor(ss, off);
  __shared__ float part[4];
  if ((threadIdx.x & 63) == 0) part[threadIdx.x >> 6] = ss;
  __syncthreads();
  const float tot = part[0] + part[1] + part[2] + part[3];
  const float s = sqrtf(2.0f / (tot + 1e-16f));
  Vs[k * 256 + c] = s * val;
}

// ---------------------------------------------------------------------------
// K2: LDS-staged Gram (64 KB, XOR chunk swizzle applied identically on store
// and read). 528 upper-triangular 2x2 tiles over 32 row-pairs; 256 threads
// need THREE passes (2 passes = 512 < 528 silently dropped the last 16 tiles
// -> a_62/a_63 of every group wrong: rounds 6-7's identical absmax 14.8).
// ---------------------------------------------------------------------------
__global__ void __launch_bounds__(256) gram_kernel(const float* __restrict__ Vs,
                                                   float* __restrict__ SS) {
  __shared__ float Vg[64 * 256];         // 64 KB
  const int g = blockIdx.x;
  const int t = threadIdx.x;

  // stage: coalesced f32x4 global loads -> swizzled b128 LDS writes
  #pragma unroll
  for (int m = 0; m < 16; ++m) {
    const int idx = t + 256 * m;         // f32x4 index within 64x256
    const int i = idx >> 6, q4 = idx & 63;
    const f32x4 v = *(const f32x4*)(Vs + (size_t)(g * 64 + i) * 256 + 4 * q4);
    *(f32x4*)(&Vg[i * 256 + ((q4 ^ (i & 7)) << 2)]) = v;
  }
  __syncthreads();

  #pragma unroll
  for (int pass = 0; pass < 3; ++pass) {   // 3*256 = 768 >= 528
    const int p = t + 256 * pass;
    if (p < 528) {
      int J = (int)((sqrtf(8.0f * (float)p + 1.0f) - 1.0f) * 0.5f);
      while ((J + 1) * (J + 2) / 2 <= p) ++J;
      while (J * (J + 1) / 2 > p) --J;
      const int I = p - J * (J + 1) / 2;
      const int ia = 2 * I, ib = 2 * I + 1, ja = 2 * J, jb = 2 * J + 1;
      const int ba = ia * 256, bb_ = ib * 256, bc = ja * 256, bd = jb * 256;
      const int ma = ia & 7, mb = ib & 7, mc = ja & 7, md = jb & 7;
      f32x4 a00 = {0,0,0,0}, a01 = {0,0,0,0}, a10 = {0,0,0,0}, a11 = {0,0,0,0};
      for (int q4 = 0; q4 < 64; ++q4) {
        const f32x4 va = *(const f32x4*)(&Vg[ba  + ((q4 ^ ma) << 2)]);
        const f32x4 vb = *(const f32x4*)(&Vg[bb_ + ((q4 ^ mb) << 2)]);
        const f32x4 vc = *(const f32x4*)(&Vg[bc  + ((q4 ^ mc) << 2)]);
        const f32x4 vd = *(const f32x4*)(&Vg[bd  + ((q4 ^ md) << 2)]);
        a00 += va * vc; a01 += va * vd; a10 += vb * vc; a11 += vb * vd;
      }
      const float s00 = (a00[0] + a00[1]) + (a00[2] + a00[3]);
      const float s01 = (a01[0] + a01[1]) + (a01[2] + a01[3]);
      const float s10 = (a10[0] + a10[1]) + (a10[2] + a10[3]);
      const float s11 = (a11[0] + a11[1]) + (a11[2] + a11[3]);
      if (ia < ja) SS[(g * 64 + ja) * 64 + ia] = s00;
      if (ia < jb) SS[(g * 64 + jb) * 64 + ia] = s01;
      if (ib < ja) SS[(g * 64 + ja) * 64 + ib] = s10;
      if (ib < jb) SS[(g * 64 + jb) * 64 + ib] = s11;
    }
  }
}

// ---------------------------------------------------------------------------
// K3: group solve (compact-WY): a_j = v_j - sum_{i<j} S[j][i] a_i.
// Thread = dim d; history in LDS (own column, no barriers); S via s_loads.
// ---------------------------------------------------------------------------
__global__ void __launch_bounds__(256) solve_kernel(const float* __restrict__ Vs,
                                                    const float* __restrict__ SS,
                                                    float* __restrict__ A) {
  __shared__ float As[64][256];    // 64 KB
  const int g = blockIdx.x, d = threadIdx.x;
  const float* __restrict__ Vg = Vs + (size_t)g * 64 * 256;
  const float* __restrict__ Sg = SS + g * 4096;
  {
    const float a0 = Vg[d];
    As[0][d] = a0;
    A[(size_t)(g * 64) * 256 + d] = a0;
  }
  for (int j = 1; j < 64; ++j) {
    float s0 = 0.f, s1 = 0.f;
    #pragma unroll 4
    for (int i = 0; i < j - 1; i += 2) {
      s0 += Sg[j * 64 + i]     * As[i][d];
      s1 += Sg[j * 64 + i + 1] * As[i + 1][d];
    }
    if (j & 1) s0 += Sg[j * 64 + (j - 1)] * As[j - 1][d];
    const float aj = Vg[j * 256 + d] - (s0 + s1);
    As[j][d] = aj;
    A[(size_t)(g * 64 + j) * 256 + d] = aj;
  }
}

// ---------------------------------------------------------------------------
// K4: dense group products, 16 rows/thread.
// Normal (g odd):  P_g[r][c]   = d_rc - sum_j A[j][r] Vs[j][c]
// Transposed (g even): P_g^T[r][c] = d_rc - sum_j Vs[j][r] A[j][c]
// ---------------------------------------------------------------------------
__global__ void __launch_bounds__(256) formp_kernel(const float* __restrict__ Vs,
                                                    const float* __restrict__ A,
                                                    float* __restrict__ outF) {
  const int rt = blockIdx.x, g = blockIdx.y;
  const int c = threadIdx.x;
  const bool tr = ((g & 1) == 0);
  const float* __restrict__ uni = (tr ? Vs : A) + (size_t)g * 64 * 256;
  const float* __restrict__ coa = (tr ? A : Vs) + (size_t)g * 64 * 256;
  float* __restrict__ Pg = outF + (size_t)g * 65536;
  float acc[16];
  #pragma unroll
  for (int r = 0; r < 16; ++r) acc[r] = (rt * 16 + r == c) ? 1.0f : 0.0f;
  for (int j = 0; j < 64; ++j) {
    const float v = coa[j * 256 + c];
    const float* __restrict__ ur = uni + j * 256 + rt * 16;
    #pragma unroll
    for (int r = 0; r < 16; ++r) acc[r] -= ur[r] * v;
  }
  #pragma unroll
  for (int r = 0; r < 16; ++r) Pg[(size_t)(rt * 16 + r) * 256 + c] = acc[r];
}

// ---------------------------------------------------------------------------
// K5: pair products. Z[r][c] = sum_k XT[k][r] Y[k][c].
// ---------------------------------------------------------------------------
__global__ void __launch_bounds__(256) mulpair_kernel(float* __restrict__ outF) {
  const int ct = blockIdx.x, rt = blockIdx.y, z = blockIdx.z;
  const float* __restrict__ XT = outF + (z == 0 ? OF_P1 : OF_P2T);
  const float* __restrict__ Y  = outF + (z == 0 ? OF_P0T : OF_P3);
  float* __restrict__ Z        = outF + (z == 0 ? OF_P01T : OF_P23);
  const int c  = ct * 64 + (threadIdx.x & 63);
  const int r0 = rt * 64 + (threadIdx.x >> 6) * 16;
  float acc[16];
  #pragma unroll
  for (int q = 0; q < 16; ++q) acc[q] = 0.f;
  for (int k = 0; k < 256; ++k) {
    const float yv = Y[k * 256 + c];
    const float* __restrict__ xr = XT + k * 256 + r0;
    #pragma unroll
    for (int q = 0; q < 16; ++q) acc[q] += xr[q] * yv;
  }
  #pragma unroll
  for (int q = 0; q < 16; ++q) Z[(size_t)(r0 + q) * 256 + c] = acc[q];
}

// ---------------------------------------------------------------------------
// K6: W = P01 * P23 -> Wb bf16.
// ---------------------------------------------------------------------------
__global__ void __launch_bounds__(256) mulfinal_kernel(const float* __restrict__ outF,
                                                       unsigned short* __restrict__ Wb) {
  const int ct = blockIdx.x, rt = blockIdx.y;
  const float* __restrict__ XT = outF + OF_P01T;
  const float* __restrict__ Y  = outF + OF_P23;
  const int c  = ct * 64 + (threadIdx.x & 63);
  const int r0 = rt * 64 + (threadIdx.x >> 6) * 16;
  float acc[16];
  #pragma unroll
  for (int q = 0; q < 16; ++q) acc[q] = 0.f;
  for (int k = 0; k < 256; ++k) {
    const float yv = Y[k * 256 + c];
    const float* __restrict__ xr = XT + k * 256 + r0;
    #pragma unroll
    for (int q = 0; q < 16; ++q) acc[q] += xr[q] * yv;
  }
  #pragma unroll
  for (int q = 0; q < 16; ++q) Wb[(size_t)(r0 + q) * 256 + c] = f2bf(acc[q]);
}

// ---------------------------------------------------------------------------
// K7: conv v2 (element-level verified): N-tile 128/block, M=256, K-tiles of
// 64, double-buffered XOR-swizzled LDS, acc[2][8].
// ---------------------------------------------------------------------------
__global__ void __launch_bounds__(512) conv_kernel(const float* __restrict__ x,
                                                   const unsigned short* __restrict__ Wb,
                                                   float* __restrict__ y) {
  __shared__ unsigned int lds[2][4096];   // 2 x 16 KB

  const int b  = blockIdx.y;
  const int n0 = blockIdx.x * 128;
  const int t  = threadIdx.x;
  const int w  = t >> 6;
  const int l  = t & 63;
  const int lr = l & 15;
  const int lg = l >> 4;
  const int nq  = t & 31;       // staging n-quad (n = 4nq..4nq+3)
  const int kb2 = t >> 5;       // 0..15; k-pairs kb2 and kb2+16

  const float* __restrict__ xb = x + (size_t)b * (256u * 4096u);
  float* __restrict__ yb = y + (size_t)b * (256u * 4096u);

  f32x4 acc[2][8];
  #pragma unroll
  for (int i = 0; i < 2; ++i)
    #pragma unroll
    for (int j = 0; j < 8; ++j)
      acc[i][j] = (f32x4){0.f, 0.f, 0.f, 0.f};

  f32x4 rg[2][2];   // [jj][k-row parity]

  auto LOAD = [&](int T) {
    #pragma unroll
    for (int jj = 0; jj < 2; ++jj) {
      const int kb = kb2 + 16 * jj;
      const f32x4* p = (const f32x4*)(xb + (size_t)(64 * T + 2 * kb) * 4096 + n0) + nq;
      rg[jj][0] = p[0];
      rg[jj][1] = p[1024];   // +4096 floats = next k-row
    }
  };
  auto STORE = [&](int buf) {
    #pragma unroll
    for (int jj = 0; jj < 2; ++jj) {
      const int kb = kb2 + 16 * jj;
      unsigned int packed[4];
      #pragma unroll
      for (int j = 0; j < 4; ++j)
        packed[j] = (unsigned int)f2bf(rg[jj][0][j]) | ((unsigned int)f2bf(rg[jj][1][j]) << 16);
      #pragma unroll
      for (int jj2 = 0; jj2 < 4; ++jj2) {   // rotate write order
        const int j = (jj2 + nq) & 3;
        const int n = 4 * nq + j;
        const int dw = n * 32 + ((((kb >> 2) ^ (n & 7)) << 2) | (kb & 3));
        lds[buf][dw] = packed[j];
      }
    }
  };

  LOAD(0); STORE(0); __syncthreads();
  int p = 0;
  for (int T = 0; T < 4; ++T) {
    if (T < 3) LOAD(T + 1);   // issue next-tile loads; consumed after barrier

    #pragma unroll
    for (int s = 0; s < 2; ++s) {
      short8v a[2];
      #pragma unroll
      for (int i = 0; i < 2; ++i)
        a[i] = *(const short8v*)(Wb + (size_t)(32 * w + 16 * i + lr) * 256
                                 + 64 * T + 32 * s + 8 * lg);
      #pragma unroll
      for (int jn = 0; jn < 8; ++jn) {
        const int n = 16 * jn + lr;
        const int dw = n * 32 + ((((4 * s + lg) ^ (n & 7)) << 2));
        const short8v bb = *(const short8v*)(&lds[p][dw]);
        acc[0][jn] = __builtin_amdgcn_mfma_f32_16x16x32_bf16(a[0], bb, acc[0][jn], 0, 0, 0);
        acc[1][jn] = __builtin_amdgcn_mfma_f32_16x16x32_bf16(a[1], bb, acc[1][jn], 0, 0, 0);
      }
    }

    if (T < 3) {
      __syncthreads();
      STORE(p ^ 1);
      __syncthreads();
      p ^= 1;
    }
  }

  // C/D layout (HW-verified): col = lane&15 (n), row = (lane>>4)*4 + reg (m)
  #pragma unroll
  for (int i = 0; i < 2; ++i)
    #pragma unroll
    for (int jn = 0; jn < 8; ++jn)
      #pragma unroll
      for (int rr = 0; rr < 4; ++rr) {
        const int o = 32 * w + 16 * i + 4 * lg + rr;
        yb[(size_t)o * 4096 + n0 + 16 * jn + lr] = acc[i][jn][rr];
      }
}

extern "C" void kernel_launch(void* const* d_in, const int* in_sizes, int n_in,
                              void* d_out, int out_size, void* d_ws, size_t ws_size,
                              hipStream_t stream) {
  const float* x   = (const float*)d_in[0];  // fp32 [32,256,64,64]
  const float* ldj = (const float*)d_in[1];  // fp32 [32]
  const float* z   = (const float*)d_in[2];  // fp32 [32,16]
  const float* V   = (const float*)d_in[3];  // fp32 [255,256]
  float* out = (float*)d_out;

  float* wsF = (float*)d_ws;
  float* Vs = wsF + WSF_VS;
  float* SS = wsF + WSF_SS;
  float* A  = wsF + WSF_A;
  unsigned short* Wb = (unsigned short*)((char*)d_ws + (size_t)(WSF_A + 65536) * 4);

  prep_kernel<<<257, 256, 0, stream>>>(V, Vs, ldj, z, out);
  gram_kernel<<<4, 256, 0, stream>>>(Vs, SS);
  solve_kernel<<<4, 256, 0, stream>>>(Vs, SS, A);
  formp_kernel<<<dim3(16, 4), 256, 0, stream>>>(Vs, A, out);
  mulpair_kernel<<<dim3(4, 4, 2), 256, 0, stream>>>(out);
  mulfinal_kernel<<<dim3(4, 4), 256, 0, stream>>>(out, Wb);
  dim3 grid(32, 32);
  conv_kernel<<<grid, 512, 0, stream>>>(x, Wb, out);
}

// Round 9
// 239.276 us; speedup vs baseline: 1.5573x; 1.0136x over previous
//
#include <hip/hip_runtime.h>
#include <stdint.h>

typedef __attribute__((ext_vector_type(8))) short short8v;   // 8 x bf16 (4 VGPR)
typedef __attribute__((ext_vector_type(4))) float f32x4;

__device__ __forceinline__ unsigned short f2bf(float f) {
  union { float f; unsigned int i; } v; v.f = f;
  unsigned int x = v.i;
  x += 0x7FFFu + ((x >> 16) & 1u);   // round-to-nearest-even
  return (unsigned short)(x >> 16);
}

// ws float offsets
#define WSF_VS 0         // [256][256] fp32 (row 255 zeroed)
#define WSF_SS 65536     // [4][64][64] fp32 Gram: SS[g*4096 + j*64 + i] = v_i.v_j (i<j)
#define WSF_A  81920     // [256][256] fp32: row g*64+j = a_j of group g
// d_out float offsets (scratch; overwritten by y later)
#define OF_P0T 0
#define OF_P1  65536
#define OF_P2T 131072
#define OF_P3  196608
#define OF_P01T 262144
#define OF_P23  327680

// ---------------------------------------------------------------------------
// K1: blocks 0..254: Vs[k] = sqrt(2/(||vfull||^2+1e-16)) * vfull.
// Block 255: Vs row 255 = 0. Block 256: tail passthrough.
// ---------------------------------------------------------------------------
__global__ void __launch_bounds__(256) prep_kernel(const float* __restrict__ V,
                                                   float* __restrict__ Vs,
                                                   const float* __restrict__ ldj,
                                                   const float* __restrict__ z,
                                                   float* __restrict__ out) {
  const int k = blockIdx.x;
  const int c = threadIdx.x;
  if (k == 256) {
    if (c < 32) out[33554432u + c] = ldj[c];
    out[33554464u + c] = z[c];
    out[33554464u + 256u + c] = z[256u + c];
    return;
  }
  if (k == 255) { Vs[255 * 256 + c] = 0.0f; return; }
  float val = (c >= 254 - k) ? V[k * 256 + c] : 1.0f;
  float ss = val * val;
  #pragma unroll
  for (int off = 32; off >= 1; off >>= 1) ss += __shfl_xor(ss, off);
  __shared__ float part[4];
  if ((threadIdx.x & 63) == 0) part[threadIdx.x >> 6] = ss;
  __syncthreads();
  const float tot = part[0] + part[1] + part[2] + part[3];
  const float s = sqrtf(2.0f / (tot + 1e-16f));
  Vs[k * 256 + c] = s * val;
}

// ---------------------------------------------------------------------------
// K2: LDS-staged Gram (known-correct R8 algebra), tile passes spread across
// blocks: grid (3 passes, 4 groups). 528 upper-tri 2x2 tiles; pass p covers
// tiles [256p, 256p+256).
// ---------------------------------------------------------------------------
__global__ void __launch_bounds__(256) gram_kernel(const float* __restrict__ Vs,
                                                   float* __restrict__ SS) {
  __shared__ float Vg[64 * 256];         // 64 KB
  const int g = blockIdx.y;
  const int t = threadIdx.x;

  #pragma unroll
  for (int m = 0; m < 16; ++m) {
    const int idx = t + 256 * m;         // f32x4 index within 64x256
    const int i = idx >> 6, q4 = idx & 63;
    const f32x4 v = *(const f32x4*)(Vs + (size_t)(g * 64 + i) * 256 + 4 * q4);
    *(f32x4*)(&Vg[i * 256 + ((q4 ^ (i & 7)) << 2)]) = v;
  }
  __syncthreads();

  const int p = t + 256 * blockIdx.x;
  if (p < 528) {
    int J = (int)((sqrtf(8.0f * (float)p + 1.0f) - 1.0f) * 0.5f);
    while ((J + 1) * (J + 2) / 2 <= p) ++J;
    while (J * (J + 1) / 2 > p) --J;
    const int I = p - J * (J + 1) / 2;
    const int ia = 2 * I, ib = 2 * I + 1, ja = 2 * J, jb = 2 * J + 1;
    const int ba = ia * 256, bb_ = ib * 256, bc = ja * 256, bd = jb * 256;
    const int ma = ia & 7, mb = ib & 7, mc = ja & 7, md = jb & 7;
    f32x4 a00 = {0,0,0,0}, a01 = {0,0,0,0}, a10 = {0,0,0,0}, a11 = {0,0,0,0};
    for (int q4 = 0; q4 < 64; ++q4) {
      const f32x4 va = *(const f32x4*)(&Vg[ba  + ((q4 ^ ma) << 2)]);
      const f32x4 vb = *(const f32x4*)(&Vg[bb_ + ((q4 ^ mb) << 2)]);
      const f32x4 vc = *(const f32x4*)(&Vg[bc  + ((q4 ^ mc) << 2)]);
      const f32x4 vd = *(const f32x4*)(&Vg[bd  + ((q4 ^ md) << 2)]);
      a00 += va * vc; a01 += va * vd; a10 += vb * vc; a11 += vb * vd;
    }
    const float s00 = (a00[0] + a00[1]) + (a00[2] + a00[3]);
    const float s01 = (a01[0] + a01[1]) + (a01[2] + a01[3]);
    const float s10 = (a10[0] + a10[1]) + (a10[2] + a10[3]);
    const float s11 = (a11[0] + a11[1]) + (a11[2] + a11[3]);
    if (ia < ja) SS[(g * 64 + ja) * 64 + ia] = s00;
    if (ia < jb) SS[(g * 64 + jb) * 64 + ia] = s01;
    if (ib < ja) SS[(g * 64 + ja) * 64 + ib] = s10;
    if (ib < jb) SS[(g * 64 + jb) * 64 + ib] = s11;
  }
}

// ---------------------------------------------------------------------------
// K3 v2: group solve a_j = v_j - sum_{i<j} S[j][i] a_i.
// FIX for the 108us disease: S staged into LDS (no SMEM s_loads mixing with
// ds_reads on lgkmcnt); history read as per-lane ds_read_b128 (lane owns 4 d).
// One wave per block, 4 blocks.
// ---------------------------------------------------------------------------
__global__ void __launch_bounds__(64) solve_kernel(const float* __restrict__ Vs,
                                                   const float* __restrict__ SS,
                                                   float* __restrict__ A) {
  __shared__ float S[4096];        // 16 KB
  __shared__ f32x4 As[64][64];     // 64 KB: As[i][lane] = a_i[4l..4l+3]
  const int g = blockIdx.x, l = threadIdx.x;   // l = 0..63
  const float* __restrict__ Vg = Vs + (size_t)g * 64 * 256;

  #pragma unroll
  for (int m = 0; m < 16; ++m)
    ((f32x4*)S)[l + 64 * m] = ((const f32x4*)(SS + g * 4096))[l + 64 * m];
  __syncthreads();

  {
    const f32x4 a0 = *(const f32x4*)(Vg + 4 * l);
    As[0][l] = a0;
    *(f32x4*)(A + (size_t)(g * 64) * 256 + 4 * l) = a0;
  }
  for (int j = 1; j < 64; ++j) {
    f32x4 s0 = {0,0,0,0}, s1 = {0,0,0,0};
    for (int i = 0; i + 1 < j; i += 2) {
      s0 += S[j * 64 + i]     * As[i][l];      // S: uniform LDS broadcast
      s1 += S[j * 64 + i + 1] * As[i + 1][l];  // As: per-lane b128
    }
    if (j & 1) s0 += S[j * 64 + (j - 1)] * As[j - 1][l];
    const f32x4 aj = *(const f32x4*)(Vg + j * 256 + 4 * l) - (s0 + s1);
    As[j][l] = aj;
    *(f32x4*)(A + (size_t)(g * 64 + j) * 256 + 4 * l) = aj;
  }
}

// ---------------------------------------------------------------------------
// K4: dense group products, 16 rows/thread; j-loop unrolled for s_load
// prefetch depth.
// ---------------------------------------------------------------------------
__global__ void __launch_bounds__(256) formp_kernel(const float* __restrict__ Vs,
                                                    const float* __restrict__ A,
                                                    float* __restrict__ outF) {
  const int rt = blockIdx.x, g = blockIdx.y;
  const int c = threadIdx.x;
  const bool tr = ((g & 1) == 0);
  const float* __restrict__ uni = (tr ? Vs : A) + (size_t)g * 64 * 256;
  const float* __restrict__ coa = (tr ? A : Vs) + (size_t)g * 64 * 256;
  float* __restrict__ Pg = outF + (size_t)g * 65536;
  float acc[16];
  #pragma unroll
  for (int r = 0; r < 16; ++r) acc[r] = (rt * 16 + r == c) ? 1.0f : 0.0f;
  #pragma unroll 2
  for (int j = 0; j < 64; ++j) {
    const float v = coa[j * 256 + c];
    const float* __restrict__ ur = uni + j * 256 + rt * 16;
    #pragma unroll
    for (int r = 0; r < 16; ++r) acc[r] -= ur[r] * v;
  }
  #pragma unroll
  for (int r = 0; r < 16; ++r) Pg[(size_t)(rt * 16 + r) * 256 + c] = acc[r];
}

// ---------------------------------------------------------------------------
// K5: pair products. Z[r][c] = sum_k XT[k][r] Y[k][c]. k-loop unrolled 4 for
// s_load prefetch.
// ---------------------------------------------------------------------------
__global__ void __launch_bounds__(256) mulpair_kernel(float* __restrict__ outF) {
  const int ct = blockIdx.x, rt = blockIdx.y, z = blockIdx.z;
  const float* __restrict__ XT = outF + (z == 0 ? OF_P1 : OF_P2T);
  const float* __restrict__ Y  = outF + (z == 0 ? OF_P0T : OF_P3);
  float* __restrict__ Z        = outF + (z == 0 ? OF_P01T : OF_P23);
  const int c  = ct * 64 + (threadIdx.x & 63);
  const int r0 = rt * 64 + (threadIdx.x >> 6) * 16;
  float acc[16];
  #pragma unroll
  for (int q = 0; q < 16; ++q) acc[q] = 0.f;
  #pragma unroll 4
  for (int k = 0; k < 256; ++k) {
    const float yv = Y[k * 256 + c];
    const float* __restrict__ xr = XT + k * 256 + r0;
    #pragma unroll
    for (int q = 0; q < 16; ++q) acc[q] += xr[q] * yv;
  }
  #pragma unroll
  for (int q = 0; q < 16; ++q) Z[(size_t)(r0 + q) * 256 + c] = acc[q];
}

// ---------------------------------------------------------------------------
// K6: W = P01 * P23 -> Wb bf16. k-loop unrolled 4.
// ---------------------------------------------------------------------------
__global__ void __launch_bounds__(256) mulfinal_kernel(const float* __restrict__ outF,
                                                       unsigned short* __restrict__ Wb) {
  const int ct = blockIdx.x, rt = blockIdx.y;
  const float* __restrict__ XT = outF + OF_P01T;
  const float* __restrict__ Y  = outF + OF_P23;
  const int c  = ct * 64 + (threadIdx.x & 63);
  const int r0 = rt * 64 + (threadIdx.x >> 6) * 16;
  float acc[16];
  #pragma unroll
  for (int q = 0; q < 16; ++q) acc[q] = 0.f;
  #pragma unroll 4
  for (int k = 0; k < 256; ++k) {
    const float yv = Y[k * 256 + c];
    const float* __restrict__ xr = XT + k * 256 + r0;
    #pragma unroll
    for (int q = 0; q < 16; ++q) acc[q] += xr[q] * yv;
  }
  #pragma unroll
  for (int q = 0; q < 16; ++q) Wb[(size_t)(r0 + q) * 256 + c] = f2bf(acc[q]);
}

// ---------------------------------------------------------------------------
// K7: conv v3 — single-stage. Whole K=256 staged once into 64 KB LDS
// ([n=128][kp=128] dw, XOR swizzle: dw = n*128 + (((kp>>2)^(n&7))<<2|(kp&3))),
// ONE barrier, then 8 k-steps x 16 MFMA uninterrupted. 16 upfront global
// loads per thread (full MLP). Reads conflict-free, stores 4-way (rotated).
// ---------------------------------------------------------------------------
__global__ void __launch_bounds__(512) conv_kernel(const float* __restrict__ x,
                                                   const unsigned short* __restrict__ Wb,
                                                   float* __restrict__ y) {
  __shared__ unsigned int lds[16384];   // 64 KB

  const int b  = blockIdx.y;
  const int n0 = blockIdx.x * 128;
  const int t  = threadIdx.x;
  const int w  = t >> 6;
  const int l  = t & 63;
  const int lr = l & 15;
  const int lg = l >> 4;
  const int nq = t & 31;        // staging n-quad (n = 4nq..4nq+3)
  const int pr = t >> 5;        // 0..15; pair-rows pr+16m

  const float* __restrict__ xb = x + (size_t)b * (256u * 4096u);
  float* __restrict__ yb = y + (size_t)b * (256u * 4096u);

  // ---- stage: issue all 16 loads, then pack+write, one barrier ----
  f32x4 r0[8], r1[8];
  #pragma unroll
  for (int m = 0; m < 8; ++m) {
    const int p = pr + 16 * m;                       // kp pair-row (k=2p,2p+1)
    const float* base = xb + (size_t)(2 * p) * 4096 + n0 + 4 * nq;
    r0[m] = *(const f32x4*)base;
    r1[m] = *(const f32x4*)(base + 4096);
  }
  #pragma unroll
  for (int m = 0; m < 8; ++m) {
    const int p = pr + 16 * m;
    unsigned int packed[4];
    #pragma unroll
    for (int j = 0; j < 4; ++j)
      packed[j] = (unsigned int)f2bf(r0[m][j]) | ((unsigned int)f2bf(r1[m][j]) << 16);
    #pragma unroll
    for (int jj = 0; jj < 4; ++jj) {                 // rotate: spread n&7
      const int j = (jj + nq) & 3;
      const int n = 4 * nq + j;
      lds[n * 128 + ((((p >> 2) ^ (n & 7)) << 2) | (p & 3))] = packed[j];
    }
  }
  __syncthreads();

  // ---- compute: 8 k-steps, no further barriers ----
  f32x4 acc[2][8];
  #pragma unroll
  for (int i = 0; i < 2; ++i)
    #pragma unroll
    for (int j = 0; j < 8; ++j)
      acc[i][j] = (f32x4){0.f, 0.f, 0.f, 0.f};

  #pragma unroll
  for (int ks = 0; ks < 8; ++ks) {
    short8v a[2];
    #pragma unroll
    for (int i = 0; i < 2; ++i)
      a[i] = *(const short8v*)(Wb + (size_t)(32 * w + 16 * i + lr) * 256
                               + 32 * ks + 8 * lg);
    #pragma unroll
    for (int jn = 0; jn < 8; ++jn) {
      const int n = 16 * jn + lr;
      const short8v bb = *(const short8v*)(&lds[n * 128 + (((4 * ks + lg) ^ (n & 7)) << 2)]);
      acc[0][jn] = __builtin_amdgcn_mfma_f32_16x16x32_bf16(a[0], bb, acc[0][jn], 0, 0, 0);
      acc[1][jn] = __builtin_amdgcn_mfma_f32_16x16x32_bf16(a[1], bb, acc[1][jn], 0, 0, 0);
    }
  }

  // C/D layout (HW-verified): col = lane&15 (n), row = (lane>>4)*4 + reg (m)
  #pragma unroll
  for (int i = 0; i < 2; ++i)
    #pragma unroll
    for (int jn = 0; jn < 8; ++jn)
      #pragma unroll
      for (int rr = 0; rr < 4; ++rr) {
        const int o = 32 * w + 16 * i + 4 * lg + rr;
        yb[(size_t)o * 4096 + n0 + 16 * jn + lr] = acc[i][jn][rr];
      }
}

extern "C" void kernel_launch(void* const* d_in, const int* in_sizes, int n_in,
                              void* d_out, int out_size, void* d_ws, size_t ws_size,
                              hipStream_t stream) {
  const float* x   = (const float*)d_in[0];  // fp32 [32,256,64,64]
  const float* ldj = (const float*)d_in[1];  // fp32 [32]
  const float* z   = (const float*)d_in[2];  // fp32 [32,16]
  const float* V   = (const float*)d_in[3];  // fp32 [255,256]
  float* out = (float*)d_out;

  float* wsF = (float*)d_ws;
  float* Vs = wsF + WSF_VS;
  float* SS = wsF + WSF_SS;
  float* A  = wsF + WSF_A;
  unsigned short* Wb = (unsigned short*)((char*)d_ws + (size_t)(WSF_A + 65536) * 4);

  prep_kernel<<<257, 256, 0, stream>>>(V, Vs, ldj, z, out);
  gram_kernel<<<dim3(3, 4), 256, 0, stream>>>(Vs, SS);
  solve_kernel<<<4, 64, 0, stream>>>(Vs, SS, A);
  formp_kernel<<<dim3(16, 4), 256, 0, stream>>>(Vs, A, out);
  mulpair_kernel<<<dim3(4, 4, 2), 256, 0, stream>>>(out);
  mulfinal_kernel<<<dim3(4, 4), 256, 0, stream>>>(out, Wb);
  dim3 grid(32, 32);
  conv_kernel<<<grid, 512, 0, stream>>>(x, Wb, out);
}

// Round 10
// 187.440 us; speedup vs baseline: 1.9879x; 1.2765x over previous
//
#include <hip/hip_runtime.h>
#include <stdint.h>

typedef __attribute__((ext_vector_type(8))) short short8v;   // 8 x bf16 (4 VGPR)
typedef __attribute__((ext_vector_type(4))) float f32x4;

__device__ __forceinline__ unsigned short f2bf(float f) {
  union { float f; unsigned int i; } v; v.f = f;
  unsigned int x = v.i;
  x += 0x7FFFu + ((x >> 16) & 1u);   // round-to-nearest-even
  return (unsigned short)(x >> 16);
}

// ws float offsets
#define WSF_VS 0         // [256][256] fp32 (row 255 zeroed)
#define WSF_SS 65536     // [4][64][64] fp32 Gram TRANSPOSED: SSt[g*4096+i*64+j] = v_i.v_j (i<j)
#define WSF_A  81920     // [256][256] fp32: row g*64+j = a_j of group g
// d_out float offsets (scratch; overwritten by y later)
#define OF_P0T 0
#define OF_P1  65536
#define OF_P2T 131072
#define OF_P3  196608
#define OF_P01T 262144
#define OF_P23  327680

// ---------------------------------------------------------------------------
// K1: blocks 0..254: Vs[k] = sqrt(2/(||vfull||^2+1e-16)) * vfull.
// Block 255: Vs row 255 = 0. Block 256: tail passthrough.
// ---------------------------------------------------------------------------
__global__ void __launch_bounds__(256) prep_kernel(const float* __restrict__ V,
                                                   float* __restrict__ Vs,
                                                   const float* __restrict__ ldj,
                                                   const float* __restrict__ z,
                                                   float* __restrict__ out) {
  const int k = blockIdx.x;
  const int c = threadIdx.x;
  if (k == 256) {
    if (c < 32) out[33554432u + c] = ldj[c];
    out[33554464u + c] = z[c];
    out[33554464u + 256u + c] = z[256u + c];
    return;
  }
  if (k == 255) { Vs[255 * 256 + c] = 0.0f; return; }
  float val = (c >= 254 - k) ? V[k * 256 + c] : 1.0f;
  float ss = val * val;
  #pragma unroll
  for (int off = 32; off >= 1; off >>= 1) ss += __shfl_xor(ss, off);
  __shared__ float part[4];
  if ((threadIdx.x & 63) == 0) part[threadIdx.x >> 6] = ss;
  __syncthreads();
  const float tot = part[0] + part[1] + part[2] + part[3];
  const float s = sqrtf(2.0f / (tot + 1e-16f));
  Vs[k * 256 + c] = s * val;
}

// ---------------------------------------------------------------------------
// K2: LDS-staged Gram (R8 algebra, verified). Writes the TRANSPOSED Gram:
// SSt[i][j] = v_i.v_j for i<j (solve v3 reads contiguous rows i).
// Grid (3 passes, 4 groups); 528 upper-tri 2x2 tiles.
// ---------------------------------------------------------------------------
__global__ void __launch_bounds__(256) gram_kernel(const float* __restrict__ Vs,
                                                   float* __restrict__ SSt) {
  __shared__ float Vg[64 * 256];         // 64 KB
  const int g = blockIdx.y;
  const int t = threadIdx.x;

  #pragma unroll
  for (int m = 0; m < 16; ++m) {
    const int idx = t + 256 * m;         // f32x4 index within 64x256
    const int i = idx >> 6, q4 = idx & 63;
    const f32x4 v = *(const f32x4*)(Vs + (size_t)(g * 64 + i) * 256 + 4 * q4);
    *(f32x4*)(&Vg[i * 256 + ((q4 ^ (i & 7)) << 2)]) = v;
  }
  __syncthreads();

  const int p = t + 256 * blockIdx.x;
  if (p < 528) {
    int J = (int)((sqrtf(8.0f * (float)p + 1.0f) - 1.0f) * 0.5f);
    while ((J + 1) * (J + 2) / 2 <= p) ++J;
    while (J * (J + 1) / 2 > p) --J;
    const int I = p - J * (J + 1) / 2;
    const int ia = 2 * I, ib = 2 * I + 1, ja = 2 * J, jb = 2 * J + 1;
    const int ba = ia * 256, bb_ = ib * 256, bc = ja * 256, bd = jb * 256;
    const int ma = ia & 7, mb = ib & 7, mc = ja & 7, md = jb & 7;
    f32x4 a00 = {0,0,0,0}, a01 = {0,0,0,0}, a10 = {0,0,0,0}, a11 = {0,0,0,0};
    for (int q4 = 0; q4 < 64; ++q4) {
      const f32x4 va = *(const f32x4*)(&Vg[ba  + ((q4 ^ ma) << 2)]);
      const f32x4 vb = *(const f32x4*)(&Vg[bb_ + ((q4 ^ mb) << 2)]);
      const f32x4 vc = *(const f32x4*)(&Vg[bc  + ((q4 ^ mc) << 2)]);
      const f32x4 vd = *(const f32x4*)(&Vg[bd  + ((q4 ^ md) << 2)]);
      a00 += va * vc; a01 += va * vd; a10 += vb * vc; a11 += vb * vd;
    }
    const float s00 = (a00[0] + a00[1]) + (a00[2] + a00[3]);
    const float s01 = (a01[0] + a01[1]) + (a01[2] + a01[3]);
    const float s10 = (a10[0] + a10[1]) + (a10[2] + a10[3]);
    const float s11 = (a11[0] + a11[1]) + (a11[2] + a11[3]);
    // transposed store: row = smaller index, col = larger
    if (ia < ja) SSt[(g * 64 + ia) * 64 + ja] = s00;
    if (ia < jb) SSt[(g * 64 + ia) * 64 + jb] = s01;
    if (ib < ja) SSt[(g * 64 + ib) * 64 + ja] = s10;
    if (ib < jb) SSt[(g * 64 + ib) * 64 + jb] = s11;
  }
}

// ---------------------------------------------------------------------------
// K3 v3: group solve, SCAN form, registers only (rule #20: all indices
// compile-time). t[j] init v_j; step i: a_i = t[i] (final, store), then
// t[j] -= SSt[i][j] * t[i] for j > i. Both loops fully unrolled; per step
// 16 uniform b128 LDS reads + <=63 independent FMAs. Thread = dim d.
// ---------------------------------------------------------------------------
__global__ void __launch_bounds__(256) solve_kernel(const float* __restrict__ Vs,
                                                    const float* __restrict__ SSt,
                                                    float* __restrict__ A) {
  __shared__ float St[4096];       // 16 KB
  const int g = blockIdx.x, d = threadIdx.x;
  #pragma unroll
  for (int m = 0; m < 4; ++m)
    ((f32x4*)St)[d + 256 * m] = ((const f32x4*)(SSt + g * 4096))[d + 256 * m];
  __syncthreads();

  const float* __restrict__ Vg = Vs + (size_t)g * 64 * 256;
  float tv[64];
  #pragma unroll
  for (int j = 0; j < 64; ++j) tv[j] = Vg[j * 256 + d];   // 64 coalesced loads

  #pragma unroll
  for (int i = 0; i < 64; ++i) {
    A[(size_t)(g * 64 + i) * 256 + d] = tv[i];            // a_i final
    f32x4 srow[16];
    #pragma unroll
    for (int m = 0; m < 16; ++m) srow[m] = *(const f32x4*)(&St[i * 64 + 4 * m]);
    #pragma unroll
    for (int j = i + 1; j < 64; ++j)
      tv[j] -= srow[j >> 2][j & 3] * tv[i];
  }
}

// ---------------------------------------------------------------------------
// K4: dense group products, 16 rows/thread.
// Normal (g odd):  P_g[r][c]   = d_rc - sum_j A[j][r] Vs[j][c]
// Transposed (g even): P_g^T[r][c] = d_rc - sum_j Vs[j][r] A[j][c]
// ---------------------------------------------------------------------------
__global__ void __launch_bounds__(256) formp_kernel(const float* __restrict__ Vs,
                                                    const float* __restrict__ A,
                                                    float* __restrict__ outF) {
  const int rt = blockIdx.x, g = blockIdx.y;
  const int c = threadIdx.x;
  const bool tr = ((g & 1) == 0);
  const float* __restrict__ uni = (tr ? Vs : A) + (size_t)g * 64 * 256;
  const float* __restrict__ coa = (tr ? A : Vs) + (size_t)g * 64 * 256;
  float* __restrict__ Pg = outF + (size_t)g * 65536;
  float acc[16];
  #pragma unroll
  for (int r = 0; r < 16; ++r) acc[r] = (rt * 16 + r == c) ? 1.0f : 0.0f;
  #pragma unroll 2
  for (int j = 0; j < 64; ++j) {
    const float v = coa[j * 256 + c];
    const float* __restrict__ ur = uni + j * 256 + rt * 16;
    #pragma unroll
    for (int r = 0; r < 16; ++r) acc[r] -= ur[r] * v;
  }
  #pragma unroll
  for (int r = 0; r < 16; ++r) Pg[(size_t)(rt * 16 + r) * 256 + c] = acc[r];
}

// ---------------------------------------------------------------------------
// K5: pair products. Z[r][c] = sum_k XT[k][r] Y[k][c].
// ---------------------------------------------------------------------------
__global__ void __launch_bounds__(256) mulpair_kernel(float* __restrict__ outF) {
  const int ct = blockIdx.x, rt = blockIdx.y, z = blockIdx.z;
  const float* __restrict__ XT = outF + (z == 0 ? OF_P1 : OF_P2T);
  const float* __restrict__ Y  = outF + (z == 0 ? OF_P0T : OF_P3);
  float* __restrict__ Z        = outF + (z == 0 ? OF_P01T : OF_P23);
  const int c  = ct * 64 + (threadIdx.x & 63);
  const int r0 = rt * 64 + (threadIdx.x >> 6) * 16;
  float acc[16];
  #pragma unroll
  for (int q = 0; q < 16; ++q) acc[q] = 0.f;
  #pragma unroll 4
  for (int k = 0; k < 256; ++k) {
    const float yv = Y[k * 256 + c];
    const float* __restrict__ xr = XT + k * 256 + r0;
    #pragma unroll
    for (int q = 0; q < 16; ++q) acc[q] += xr[q] * yv;
  }
  #pragma unroll
  for (int q = 0; q < 16; ++q) Z[(size_t)(r0 + q) * 256 + c] = acc[q];
}

// ---------------------------------------------------------------------------
// K6: W = P01 * P23 -> Wb bf16.
// ---------------------------------------------------------------------------
__global__ void __launch_bounds__(256) mulfinal_kernel(const float* __restrict__ outF,
                                                       unsigned short* __restrict__ Wb) {
  const int ct = blockIdx.x, rt = blockIdx.y;
  const float* __restrict__ XT = outF + OF_P01T;
  const float* __restrict__ Y  = outF + OF_P23;
  const int c  = ct * 64 + (threadIdx.x & 63);
  const int r0 = rt * 64 + (threadIdx.x >> 6) * 16;
  float acc[16];
  #pragma unroll
  for (int q = 0; q < 16; ++q) acc[q] = 0.f;
  #pragma unroll 4
  for (int k = 0; k < 256; ++k) {
    const float yv = Y[k * 256 + c];
    const float* __restrict__ xr = XT + k * 256 + r0;
    #pragma unroll
    for (int q = 0; q < 16; ++q) acc[q] += xr[q] * yv;
  }
  #pragma unroll
  for (int q = 0; q < 16; ++q) Wb[(size_t)(r0 + q) * 256 + c] = f2bf(acc[q]);
}

// ---------------------------------------------------------------------------
// K7: conv v3 + XCD batch-grouping swizzle. hw id = by%8 + 8*(bx + 32*(by>>3))
// (bijective) -> all 32 n-tiles of a batch land on one XCD (id%8 round-robin)
// so the co-resident blocks' 512B-run reads/writes merge into full 16KB rows
// at the XCD L2 -> sequential DRAM streams. Body identical to R9 (verified).
// ---------------------------------------------------------------------------
__global__ void __launch_bounds__(512) conv_kernel(const float* __restrict__ x,
                                                   const unsigned short* __restrict__ Wb,
                                                   float* __restrict__ y) {
  __shared__ unsigned int lds[16384];   // 64 KB

  const int r  = blockIdx.x & 7, q = blockIdx.x >> 3;
  const int bx = q & 31;
  const int b  = ((q >> 5) << 3) + r;   // batch
  const int n0 = bx * 128;

  const int t  = threadIdx.x;
  const int w  = t >> 6;
  const int l  = t & 63;
  const int lr = l & 15;
  const int lg = l >> 4;
  const int nq = t & 31;        // staging n-quad (n = 4nq..4nq+3)
  const int pr = t >> 5;        // 0..15; pair-rows pr+16m

  const float* __restrict__ xb = x + (size_t)b * (256u * 4096u);
  float* __restrict__ yb = y + (size_t)b * (256u * 4096u);

  // ---- stage: issue all 16 loads, then pack+write, one barrier ----
  f32x4 r0[8], r1[8];
  #pragma unroll
  for (int m = 0; m < 8; ++m) {
    const int p = pr + 16 * m;                       // kp pair-row (k=2p,2p+1)
    const float* base = xb + (size_t)(2 * p) * 4096 + n0 + 4 * nq;
    r0[m] = *(const f32x4*)base;
    r1[m] = *(const f32x4*)(base + 4096);
  }
  #pragma unroll
  for (int m = 0; m < 8; ++m) {
    const int p = pr + 16 * m;
    unsigned int packed[4];
    #pragma unroll
    for (int j = 0; j < 4; ++j)
      packed[j] = (unsigned int)f2bf(r0[m][j]) | ((unsigned int)f2bf(r1[m][j]) << 16);
    #pragma unroll
    for (int jj = 0; jj < 4; ++jj) {                 // rotate: spread n&7
      const int j = (jj + nq) & 3;
      const int n = 4 * nq + j;
      lds[n * 128 + ((((p >> 2) ^ (n & 7)) << 2) | (p & 3))] = packed[j];
    }
  }
  __syncthreads();

  // ---- compute: 8 k-steps, no further barriers ----
  f32x4 acc[2][8];
  #pragma unroll
  for (int i = 0; i < 2; ++i)
    #pragma unroll
    for (int j = 0; j < 8; ++j)
      acc[i][j] = (f32x4){0.f, 0.f, 0.f, 0.f};

  #pragma unroll
  for (int ks = 0; ks < 8; ++ks) {
    short8v a[2];
    #pragma unroll
    for (int i = 0; i < 2; ++i)
      a[i] = *(const short8v*)(Wb + (size_t)(32 * w + 16 * i + lr) * 256
                               + 32 * ks + 8 * lg);
    #pragma unroll
    for (int jn = 0; jn < 8; ++jn) {
      const int n = 16 * jn + lr;
      const short8v bb = *(const short8v*)(&lds[n * 128 + (((4 * ks + lg) ^ (n & 7)) << 2)]);
      acc[0][jn] = __builtin_amdgcn_mfma_f32_16x16x32_bf16(a[0], bb, acc[0][jn], 0, 0, 0);
      acc[1][jn] = __builtin_amdgcn_mfma_f32_16x16x32_bf16(a[1], bb, acc[1][jn], 0, 0, 0);
    }
  }

  // C/D layout (HW-verified): col = lane&15 (n), row = (lane>>4)*4 + reg (m)
  #pragma unroll
  for (int i = 0; i < 2; ++i)
    #pragma unroll
    for (int jn = 0; jn < 8; ++jn)
      #pragma unroll
      for (int rr = 0; rr < 4; ++rr) {
        const int o = 32 * w + 16 * i + 4 * lg + rr;
        yb[(size_t)o * 4096 + n0 + 16 * jn + lr] = acc[i][jn][rr];
      }
}

extern "C" void kernel_launch(void* const* d_in, const int* in_sizes, int n_in,
                              void* d_out, int out_size, void* d_ws, size_t ws_size,
                              hipStream_t stream) {
  const float* x   = (const float*)d_in[0];  // fp32 [32,256,64,64]
  const float* ldj = (const float*)d_in[1];  // fp32 [32]
  const float* z   = (const float*)d_in[2];  // fp32 [32,16]
  const float* V   = (const float*)d_in[3];  // fp32 [255,256]
  float* out = (float*)d_out;

  float* wsF = (float*)d_ws;
  float* Vs  = wsF + WSF_VS;
  float* SSt = wsF + WSF_SS;
  float* A   = wsF + WSF_A;
  unsigned short* Wb = (unsigned short*)((char*)d_ws + (size_t)(WSF_A + 65536) * 4);

  prep_kernel<<<257, 256, 0, stream>>>(V, Vs, ldj, z, out);
  gram_kernel<<<dim3(3, 4), 256, 0, stream>>>(Vs, SSt);
  solve_kernel<<<4, 256, 0, stream>>>(Vs, SSt, A);
  formp_kernel<<<dim3(16, 4), 256, 0, stream>>>(Vs, A, out);
  mulpair_kernel<<<dim3(4, 4, 2), 256, 0, stream>>>(out);
  mulfinal_kernel<<<dim3(4, 4), 256, 0, stream>>>(out, Wb);
  conv_kernel<<<1024, 512, 0, stream>>>(x, Wb, out);
}